// Round 5
// baseline (449.313 us; speedup 1.0000x reference)
//
#include <hip/hip_runtime.h>
#include <hip/hip_bf16.h>

#define DM 768
#define NH 12
#define HD 64
#define B_ 4
#define S_ 2048
#define MT (B_*S_)   // 8192 rows

typedef unsigned short u16;
typedef __attribute__((ext_vector_type(8))) short bf16x8;
typedef __attribute__((ext_vector_type(4))) float f32x4;
typedef __attribute__((ext_vector_type(4))) short s16x4;

__device__ __forceinline__ u16 f2bf(float f) {
    union { float f; unsigned u; } x; x.f = f;
    unsigned r = x.u + 0x7fffu + ((x.u >> 16) & 1u);   // RNE
    return (u16)(r >> 16);
}

__device__ __forceinline__ unsigned pk2(float a, float b) {
    union { __hip_bfloat162 h; unsigned u; } cv;
    cv.h = __float22bfloat162_rn(float2{a, b});
    return cv.u;
}

#define GLD_LDS(gp, lp) \
    __builtin_amdgcn_global_load_lds( \
        (const __attribute__((address_space(1))) void*)(gp), \
        (__attribute__((address_space(3))) void*)(lp), 16, 0, 0)

// ---------------- fused fp32 -> bf16 conversions ----------------
__global__ void cvt3_kernel(const float* __restrict__ s0, const float* __restrict__ s1,
                            const float* __restrict__ s2,
                            u16* __restrict__ d0, u16* __restrict__ d1, u16* __restrict__ d2,
                            int blocksPer) {
    int sel = blockIdx.x / blocksPer;           // uniform per block
    int rel = blockIdx.x % blocksPer;
    const float* s = (sel == 0) ? s0 : (sel == 1) ? s1 : s2;
    u16* d = (sel == 0) ? d0 : (sel == 1) ? d1 : d2;
    int i = (rel * 256 + threadIdx.x) * 4;
    float4 v = *(const float4*)(s + i);
    s16x4 o;
    o.x = (short)f2bf(v.x); o.y = (short)f2bf(v.y);
    o.z = (short)f2bf(v.z); o.w = (short)f2bf(v.w);
    *(s16x4*)(d + i) = o;
}

__global__ void cvt4_kernel(const float* __restrict__ s0, const float* __restrict__ s1,
                            const float* __restrict__ s2, const float* __restrict__ s3,
                            u16* __restrict__ d0, u16* __restrict__ d1,
                            u16* __restrict__ d2, u16* __restrict__ d3,
                            int blocksPer) {
    int sel = blockIdx.x / blocksPer;
    int rel = blockIdx.x % blocksPer;
    const float* s = (sel == 0) ? s0 : (sel == 1) ? s1 : (sel == 2) ? s2 : s3;
    u16* d = (sel == 0) ? d0 : (sel == 1) ? d1 : (sel == 2) ? d2 : d3;
    int i = (rel * 256 + threadIdx.x) * 4;
    float4 v = *(const float4*)(s + i);
    s16x4 o;
    o.x = (short)f2bf(v.x); o.y = (short)f2bf(v.y);
    o.z = (short)f2bf(v.z); o.w = (short)f2bf(v.w);
    *(s16x4*)(d + i) = o;
}

// ---------------- shared 128x128-tile MFMA core (m97 structure) ----------------
__device__ __forceinline__ void gemm_core_128(
    const u16* __restrict__ A, const u16* __restrict__ B,
    int m0, int n0, u16* As, u16* Bs, f32x4 acc[4][4])
{
    const int tid = threadIdx.x;
    const int lane = tid & 63;
    const int lr = lane & 15, quad = lane >> 4;
    const int wave = tid >> 6;
    const int wm = (wave & 1) * 64, wn = (wave >> 1) * 64;

    for (int ks = 0; ks < 24; ++ks) {
        #pragma unroll
        for (int r = 0; r < 2; ++r) {
            int idx = r * 256 + tid;
            int row = idx >> 2, col = (idx & 3) * 8;
            GLD_LDS(A + (size_t)(m0 + row) * DM + ks * 32 + col, As + idx * 8);
            GLD_LDS(B + (size_t)(n0 + row) * DM + ks * 32 + col, Bs + idx * 8);
        }
        __syncthreads();
        bf16x8 a[4], b[4];
        #pragma unroll
        for (int i = 0; i < 4; ++i) a[i] = *(const bf16x8*)(As + (wm + i * 16 + lr) * 32 + quad * 8);
        #pragma unroll
        for (int j = 0; j < 4; ++j) b[j] = *(const bf16x8*)(Bs + (wn + j * 16 + lr) * 32 + quad * 8);
        #pragma unroll
        for (int i = 0; i < 4; ++i)
            #pragma unroll
            for (int j = 0; j < 4; ++j)
                acc[i][j] = __builtin_amdgcn_mfma_f32_16x16x32_bf16(a[i], b[j], acc[i][j], 0, 0, 0);
        __syncthreads();
    }
}

// ---------------- fused QKV projection GEMM (LDS-staged) ----------------
__global__ __launch_bounds__(256) void qkv_gemm(
    const u16* __restrict__ Xq, const u16* __restrict__ Xk, const u16* __restrict__ Xv,
    const u16* __restrict__ Wq, const u16* __restrict__ Wk, const u16* __restrict__ Wv,
    const float* __restrict__ bQ, const float* __restrict__ bK, const float* __restrict__ bV,
    u16* __restrict__ Qo, u16* __restrict__ Ko, u16* __restrict__ VTo)
{
    __shared__ __align__(16) u16 As[128 * 32];
    __shared__ __align__(16) u16 Bs[128 * 32];

    const int mat = blockIdx.x / 384;           // uniform per block
    const int t   = blockIdx.x % 384;
    const int mt  = t / 6, nt = t % 6;
    const u16* X = (mat == 0) ? Xq : (mat == 1 ? Xk : Xv);
    const u16* W = (mat == 0) ? Wq : (mat == 1 ? Wk : Wv);
    const float* bias = (mat == 0) ? bQ : (mat == 1 ? bK : bV);

    const int lane = threadIdx.x & 63;
    const int lr = lane & 15, quad = lane >> 4;
    const int wave = threadIdx.x >> 6;
    const int m0 = mt * 128 + (wave & 1) * 64;
    const int n0 = nt * 128 + (wave >> 1) * 64;

    f32x4 acc[4][4] = {};
    gemm_core_128(X, W, mt * 128, nt * 128, As, Bs, acc);

    const int bb = m0 / S_, s0 = m0 % S_, h = n0 / HD;
    if (mat < 2) {
        u16* O = (mat == 0) ? Qo : Ko;
        const float qs = (mat == 0) ? 0.18033688011112042f : 1.0f;  // (1/8)*log2(e)
        #pragma unroll
        for (int jj = 0; jj < 4; ++jj) {
            float bv = bias[n0 + jj * 16 + lr];
            #pragma unroll
            for (int i = 0; i < 4; ++i)
                #pragma unroll
                for (int r = 0; r < 4; ++r) {
                    int s = s0 + i * 16 + quad * 4 + r;
                    O[((size_t)(bb * NH + h) * S_ + s) * HD + jj * 16 + lr] = f2bf((acc[i][jj][r] + bv) * qs);
                }
        }
    } else {
        #pragma unroll
        for (int jj = 0; jj < 4; ++jj) {
            float bv = bias[n0 + jj * 16 + lr];
            #pragma unroll
            for (int i = 0; i < 4; ++i) {
                int s = s0 + i * 16 + quad * 4;
                s16x4 o;
                o.x = (short)f2bf(acc[i][jj][0] + bv);
                o.y = (short)f2bf(acc[i][jj][1] + bv);
                o.z = (short)f2bf(acc[i][jj][2] + bv);
                o.w = (short)f2bf(acc[i][jj][3] + bv);
                *(s16x4*)(VTo + ((size_t)(bb * NH + h) * HD + jj * 16 + lr) * S_ + s) = o;
            }
        }
    }
}

// ---------------- flash attention (causal, NO-max softmax, split-K 4 waves) ----------------
// Block = 4 waves, ALL on the same 32 q-rows; wave w handles K-tiles kt ≡ w (mod 4).
// Partials are additive (no-max softmax): 2-round LDS tree reduce, wave 0 stores.
// Grid 3072 = 8 xcd * 6 bh * 64 q-chunks (XCD-swizzled, longest-first).
__global__ __launch_bounds__(256, 5) void attn_kernel(
    const u16* __restrict__ Q, const u16* __restrict__ K,
    const u16* __restrict__ VT, u16* __restrict__ CTX)
{
    const int tid = threadIdx.x;
    const int wave = tid >> 6;
    const int lane = tid & 63;
    const int lr = lane & 15, quad = lane >> 4;
    const int xcd = blockIdx.x & 7;
    const int idx = blockIdx.x >> 3;            // 0..383
    const int bh  = xcd * 6 + (idx % 6);
    const int qw  = 63 - (idx / 6);             // longest q-chunks first
    const int q0  = qw * 32;
    const u16* Qb = Q  + (size_t)bh * S_ * HD;
    const u16* Kb = K  + (size_t)bh * S_ * HD;
    const u16* Vb = VT + (size_t)bh * HD * S_;

    // union: per-wave score transpose buf (4*16*68 floats) | reduction buf (2*64*44)
    __shared__ __align__(16) float smem[2 * 64 * 44];   // 5632 floats = 22528 B
    float* pbuf = smem + wave * (16 * 68);

    bf16x8 aq[2][2];
    #pragma unroll
    for (int mi = 0; mi < 2; ++mi)
        #pragma unroll
        for (int kk = 0; kk < 2; ++kk)
            aq[mi][kk] = *(const bf16x8*)(Qb + (size_t)(q0 + mi * 16 + lr) * HD + kk * 32 + quad * 8);

    f32x4 o[2][4] = {};
    f32x4 lacc[2] = {};
    bf16x8 ones;
    #pragma unroll
    for (int j = 0; j < 8; ++j) ones[j] = (short)0x3F80;   // bf16 1.0

    const int ktmax = (q0 + 31) >> 6;

    for (int kt = wave; kt <= ktmax; kt += 4) {
        const int k0 = kt << 6;

        bf16x8 bk[4][2];
        #pragma unroll
        for (int nt = 0; nt < 4; ++nt)
            #pragma unroll
            for (int kk = 0; kk < 2; ++kk)
                bk[nt][kk] = *(const bf16x8*)(Kb + (size_t)(k0 + nt * 16 + lr) * HD + kk * 32 + quad * 8);
        bf16x8 bv[4][2];
        #pragma unroll
        for (int nv = 0; nv < 4; ++nv)
            #pragma unroll
            for (int c = 0; c < 2; ++c)
                bv[nv][c] = *(const bf16x8*)(Vb + (size_t)(nv * 16 + lr) * S_ + k0 + c * 32 + quad * 8);

        f32x4 sc[2][4];
        #pragma unroll
        for (int mi = 0; mi < 2; ++mi)
            #pragma unroll
            for (int nt = 0; nt < 4; ++nt) {
                f32x4 z = {0.f, 0.f, 0.f, 0.f};
                z = __builtin_amdgcn_mfma_f32_16x16x32_bf16(aq[mi][0], bk[nt][0], z, 0, 0, 0);
                z = __builtin_amdgcn_mfma_f32_16x16x32_bf16(aq[mi][1], bk[nt][1], z, 0, 0, 0);
                sc[mi][nt] = z;
            }

        if (kt == ktmax) {   // diagonal tile: causal mask (exp2(-inf) = 0)
            #pragma unroll
            for (int mi = 0; mi < 2; ++mi)
                #pragma unroll
                for (int nt = 0; nt < 4; ++nt)
                    #pragma unroll
                    for (int r = 0; r < 4; ++r) {
                        int row = q0 + mi * 16 + quad * 4 + r;
                        int col = k0 + nt * 16 + lr;
                        if (col > row) sc[mi][nt][r] = -INFINITY;
                    }
        }

        // exp in C-layout; Q pre-scaled by scale*log2e
        #pragma unroll
        for (int mi = 0; mi < 2; ++mi)
            #pragma unroll
            for (int nt = 0; nt < 4; ++nt)
                #pragma unroll
                for (int r = 0; r < 4; ++r)
                    sc[mi][nt][r] = exp2f(sc[mi][nt][r]);

        // C-layout -> A-layout via per-wave LDS (wave-synchronous), mi sequential to halve LDS
        bf16x8 pa[2][2];
        #pragma unroll
        for (int mi = 0; mi < 2; ++mi) {
            #pragma unroll
            for (int r = 0; r < 4; ++r) {
                float* bp = &pbuf[(quad * 4 + r) * 68 + lr];
                bp[0]  = sc[mi][0][r];
                bp[16] = sc[mi][1][r];
                bp[32] = sc[mi][2][r];
                bp[48] = sc[mi][3][r];
            }
            #pragma unroll
            for (int c = 0; c < 2; ++c) {
                const float* rp = &pbuf[lr * 68 + c * 32 + quad * 8];
                union { unsigned u[4]; bf16x8 v; } P;
                #pragma unroll
                for (int p = 0; p < 4; ++p)
                    P.u[p] = pk2(rp[2 * p], rp[2 * p + 1]);
                pa[mi][c] = P.v;
            }
        }

        #pragma unroll
        for (int mi = 0; mi < 2; ++mi) {
            lacc[mi] = __builtin_amdgcn_mfma_f32_16x16x32_bf16(pa[mi][0], ones, lacc[mi], 0, 0, 0);
            lacc[mi] = __builtin_amdgcn_mfma_f32_16x16x32_bf16(pa[mi][1], ones, lacc[mi], 0, 0, 0);
            #pragma unroll
            for (int nv = 0; nv < 4; ++nv) {
                o[mi][nv] = __builtin_amdgcn_mfma_f32_16x16x32_bf16(pa[mi][0], bv[nv][0], o[mi][nv], 0, 0, 0);
                o[mi][nv] = __builtin_amdgcn_mfma_f32_16x16x32_bf16(pa[mi][1], bv[nv][1], o[mi][nv], 0, 0, 0);
            }
        }
    }

    // -------- cross-wave reduction (partials are additive) --------
    __syncthreads();
    float* red = smem;          // [2][64][44]
    if (wave >= 2) {
        float* rp = red + (wave - 2) * (64 * 44) + lane * 44;
        #pragma unroll
        for (int mi = 0; mi < 2; ++mi) {
            #pragma unroll
            for (int nv = 0; nv < 4; ++nv)
                *(f32x4*)(rp + (mi * 4 + nv) * 4) = o[mi][nv];
            *(f32x4*)(rp + 32 + mi * 4) = lacc[mi];
        }
    }
    __syncthreads();
    if (wave < 2) {
        const float* rp = red + wave * (64 * 44) + lane * 44;
        #pragma unroll
        for (int mi = 0; mi < 2; ++mi) {
            #pragma unroll
            for (int nv = 0; nv < 4; ++nv)
                o[mi][nv] += *(const f32x4*)(rp + (mi * 4 + nv) * 4);
            lacc[mi] += *(const f32x4*)(rp + 32 + mi * 4);
        }
    }
    __syncthreads();
    if (wave == 1) {
        float* rp = red + lane * 44;
        #pragma unroll
        for (int mi = 0; mi < 2; ++mi) {
            #pragma unroll
            for (int nv = 0; nv < 4; ++nv)
                *(f32x4*)(rp + (mi * 4 + nv) * 4) = o[mi][nv];
            *(f32x4*)(rp + 32 + mi * 4) = lacc[mi];
        }
    }
    __syncthreads();
    if (wave == 0) {
        const float* rp = red + lane * 44;
        #pragma unroll
        for (int mi = 0; mi < 2; ++mi) {
            #pragma unroll
            for (int nv = 0; nv < 4; ++nv)
                o[mi][nv] += *(const f32x4*)(rp + (mi * 4 + nv) * 4);
            lacc[mi] += *(const f32x4*)(rp + 32 + mi * 4);
        }
        const int bb = bh / NH, h = bh % NH;
        #pragma unroll
        for (int mi = 0; mi < 2; ++mi) {
            f32x4 inv;
            #pragma unroll
            for (int r = 0; r < 4; ++r) inv[r] = 1.0f / lacc[mi][r];
            #pragma unroll
            for (int nv = 0; nv < 4; ++nv)
                #pragma unroll
                for (int r = 0; r < 4; ++r)
                    CTX[(size_t)(bb * S_ + q0 + mi * 16 + quad * 4 + r) * DM + h * HD + nv * 16 + lr]
                        = f2bf(o[mi][nv][r] * inv[r]);
        }
    }
}

// ---------------- output projection GEMM (LDS-staged, fp32 out) ----------------
__global__ __launch_bounds__(256) void o_gemm(
    const u16* __restrict__ X, const u16* __restrict__ W,
    const float* __restrict__ bias, float* __restrict__ Out)
{
    __shared__ __align__(16) u16 As[128 * 32];
    __shared__ __align__(16) u16 Bs[128 * 32];

    const int mt = blockIdx.x / 6, nt = blockIdx.x % 6;
    const int lane = threadIdx.x & 63;
    const int lr = lane & 15, quad = lane >> 4;
    const int wave = threadIdx.x >> 6;
    const int m0 = mt * 128 + (wave & 1) * 64;
    const int n0 = nt * 128 + (wave >> 1) * 64;

    f32x4 acc[4][4] = {};
    gemm_core_128(X, W, mt * 128, nt * 128, As, Bs, acc);

    #pragma unroll
    for (int jj = 0; jj < 4; ++jj) {
        float bv = bias[n0 + jj * 16 + lr];
        #pragma unroll
        for (int i = 0; i < 4; ++i)
            #pragma unroll
            for (int r = 0; r < 4; ++r)
                Out[(size_t)(m0 + i * 16 + quad * 4 + r) * DM + n0 + jj * 16 + lr] = acc[i][jj][r] + bv;
    }
}

extern "C" void kernel_launch(void* const* d_in, const int* in_sizes, int n_in,
                              void* d_out, int out_size, void* d_ws, size_t ws_size,
                              hipStream_t stream) {
    const float* q  = (const float*)d_in[0];
    const float* k  = (const float*)d_in[1];
    const float* v  = (const float*)d_in[2];
    const float* WQ = (const float*)d_in[3];
    const float* bQ = (const float*)d_in[4];
    const float* WK = (const float*)d_in[5];
    const float* bK = (const float*)d_in[6];
    const float* WV = (const float*)d_in[7];
    const float* bV = (const float*)d_in[8];
    const float* WO = (const float*)d_in[9];
    const float* bO = (const float*)d_in[10];

    char* ws = (char*)d_ws;
    const size_t SZ_X = (size_t)MT * DM * 2;   // 12,582,912 B
    const size_t SZ_W = (size_t)DM * DM * 2;   //  1,179,648 B
    u16* Xq = (u16*)(ws);
    u16* Xk = (u16*)(ws + SZ_X);
    u16* Xv = (u16*)(ws + 2 * SZ_X);
    u16* Wq = (u16*)(ws + 3 * SZ_X);
    u16* Wk = (u16*)(ws + 3 * SZ_X + SZ_W);
    u16* Wv = (u16*)(ws + 3 * SZ_X + 2 * SZ_W);
    u16* Wo = (u16*)(ws + 3 * SZ_X + 3 * SZ_W);
    u16* Qh  = (u16*)(ws + 3 * SZ_X + 4 * SZ_W);
    u16* Kh  = (u16*)(ws + 4 * SZ_X + 4 * SZ_W);
    u16* VTh = (u16*)(ws + 5 * SZ_X + 4 * SZ_W);
    u16* CTX = Xq;   // Xq dead after qkv_gemm; reuse

    const int nX = MT * DM;    // 6,291,456
    const int nW = DM * DM;    //   589,824
    cvt3_kernel<<<3 * (nX / 1024), 256, 0, stream>>>(q, k, v, Xq, Xk, Xv, nX / 1024);
    cvt4_kernel<<<4 * (nW / 1024), 256, 0, stream>>>(WQ, WK, WV, WO, Wq, Wk, Wv, Wo, nW / 1024);

    qkv_gemm<<<1152, 256, 0, stream>>>(Xq, Xk, Xv, Wq, Wk, Wv, bQ, bK, bV, Qh, Kh, VTh);
    attn_kernel<<<3072, 256, 0, stream>>>(Qh, Kh, VTh, CTX);
    o_gemm<<<384, 256, 0, stream>>>(CTX, Wo, bO, (float*)d_out);
}

// Round 6
// 316.254 us; speedup vs baseline: 1.4207x; 1.4207x over previous
//
#include <hip/hip_runtime.h>
#include <hip/hip_bf16.h>

#define DM 768
#define NH 12
#define HD 64
#define B_ 4
#define S_ 2048
#define MT (B_*S_)   // 8192 rows

typedef unsigned short u16;
typedef __attribute__((ext_vector_type(8))) short bf16x8;
typedef __attribute__((ext_vector_type(4))) float f32x4;
typedef __attribute__((ext_vector_type(4))) short s16x4;

__device__ __forceinline__ u16 f2bf(float f) {
    union { float f; unsigned u; } x; x.f = f;
    unsigned r = x.u + 0x7fffu + ((x.u >> 16) & 1u);   // RNE
    return (u16)(r >> 16);
}

__device__ __forceinline__ unsigned pk2(float a, float b) {
    union { __hip_bfloat162 h; unsigned u; } cv;
    cv.h = __float22bfloat162_rn(float2{a, b});
    return cv.u;
}

#define GLD_LDS(gp, lp) \
    __builtin_amdgcn_global_load_lds( \
        (const __attribute__((address_space(1))) void*)(gp), \
        (__attribute__((address_space(3))) void*)(lp), 16, 0, 0)

// ---------------- fused fp32 -> bf16 conversions ----------------
__global__ void cvt3_kernel(const float* __restrict__ s0, const float* __restrict__ s1,
                            const float* __restrict__ s2,
                            u16* __restrict__ d0, u16* __restrict__ d1, u16* __restrict__ d2,
                            int blocksPer) {
    int sel = blockIdx.x / blocksPer;           // uniform per block
    int rel = blockIdx.x % blocksPer;
    const float* s = (sel == 0) ? s0 : (sel == 1) ? s1 : s2;
    u16* d = (sel == 0) ? d0 : (sel == 1) ? d1 : d2;
    int i = (rel * 256 + threadIdx.x) * 4;
    float4 v = *(const float4*)(s + i);
    s16x4 o;
    o.x = (short)f2bf(v.x); o.y = (short)f2bf(v.y);
    o.z = (short)f2bf(v.z); o.w = (short)f2bf(v.w);
    *(s16x4*)(d + i) = o;
}

__global__ void cvt4_kernel(const float* __restrict__ s0, const float* __restrict__ s1,
                            const float* __restrict__ s2, const float* __restrict__ s3,
                            u16* __restrict__ d0, u16* __restrict__ d1,
                            u16* __restrict__ d2, u16* __restrict__ d3,
                            int blocksPer) {
    int sel = blockIdx.x / blocksPer;
    int rel = blockIdx.x % blocksPer;
    const float* s = (sel == 0) ? s0 : (sel == 1) ? s1 : (sel == 2) ? s2 : s3;
    u16* d = (sel == 0) ? d0 : (sel == 1) ? d1 : (sel == 2) ? d2 : d3;
    int i = (rel * 256 + threadIdx.x) * 4;
    float4 v = *(const float4*)(s + i);
    s16x4 o;
    o.x = (short)f2bf(v.x); o.y = (short)f2bf(v.y);
    o.z = (short)f2bf(v.z); o.w = (short)f2bf(v.w);
    *(s16x4*)(d + i) = o;
}

// ---------------- shared 128x128-tile MFMA core (m97 structure) ----------------
__device__ __forceinline__ void gemm_core_128(
    const u16* __restrict__ A, const u16* __restrict__ B,
    int m0, int n0, u16* As, u16* Bs, f32x4 acc[4][4])
{
    const int tid = threadIdx.x;
    const int lane = tid & 63;
    const int lr = lane & 15, quad = lane >> 4;
    const int wave = tid >> 6;
    const int wm = (wave & 1) * 64, wn = (wave >> 1) * 64;

    for (int ks = 0; ks < 24; ++ks) {
        #pragma unroll
        for (int r = 0; r < 2; ++r) {
            int idx = r * 256 + tid;
            int row = idx >> 2, col = (idx & 3) * 8;
            GLD_LDS(A + (size_t)(m0 + row) * DM + ks * 32 + col, As + idx * 8);
            GLD_LDS(B + (size_t)(n0 + row) * DM + ks * 32 + col, Bs + idx * 8);
        }
        __syncthreads();
        bf16x8 a[4], b[4];
        #pragma unroll
        for (int i = 0; i < 4; ++i) a[i] = *(const bf16x8*)(As + (wm + i * 16 + lr) * 32 + quad * 8);
        #pragma unroll
        for (int j = 0; j < 4; ++j) b[j] = *(const bf16x8*)(Bs + (wn + j * 16 + lr) * 32 + quad * 8);
        #pragma unroll
        for (int i = 0; i < 4; ++i)
            #pragma unroll
            for (int j = 0; j < 4; ++j)
                acc[i][j] = __builtin_amdgcn_mfma_f32_16x16x32_bf16(a[i], b[j], acc[i][j], 0, 0, 0);
        __syncthreads();
    }
}

// ---------------- fused QKV projection GEMM (LDS-staged) ----------------
__global__ __launch_bounds__(256) void qkv_gemm(
    const u16* __restrict__ Xq, const u16* __restrict__ Xk, const u16* __restrict__ Xv,
    const u16* __restrict__ Wq, const u16* __restrict__ Wk, const u16* __restrict__ Wv,
    const float* __restrict__ bQ, const float* __restrict__ bK, const float* __restrict__ bV,
    u16* __restrict__ Qo, u16* __restrict__ Ko, u16* __restrict__ VTo)
{
    __shared__ __align__(16) u16 As[128 * 32];
    __shared__ __align__(16) u16 Bs[128 * 32];

    const int mat = blockIdx.x / 384;           // uniform per block
    const int t   = blockIdx.x % 384;
    const int mt  = t / 6, nt = t % 6;
    const u16* X = (mat == 0) ? Xq : (mat == 1 ? Xk : Xv);
    const u16* W = (mat == 0) ? Wq : (mat == 1 ? Wk : Wv);
    const float* bias = (mat == 0) ? bQ : (mat == 1 ? bK : bV);

    const int lane = threadIdx.x & 63;
    const int lr = lane & 15, quad = lane >> 4;
    const int wave = threadIdx.x >> 6;
    const int m0 = mt * 128 + (wave & 1) * 64;
    const int n0 = nt * 128 + (wave >> 1) * 64;

    f32x4 acc[4][4] = {};
    gemm_core_128(X, W, mt * 128, nt * 128, As, Bs, acc);

    const int bb = m0 / S_, s0 = m0 % S_, h = n0 / HD;
    if (mat < 2) {
        u16* O = (mat == 0) ? Qo : Ko;
        const float qs = (mat == 0) ? 0.18033688011112042f : 1.0f;  // (1/8)*log2(e)
        #pragma unroll
        for (int jj = 0; jj < 4; ++jj) {
            float bv = bias[n0 + jj * 16 + lr];
            #pragma unroll
            for (int i = 0; i < 4; ++i)
                #pragma unroll
                for (int r = 0; r < 4; ++r) {
                    int s = s0 + i * 16 + quad * 4 + r;
                    O[((size_t)(bb * NH + h) * S_ + s) * HD + jj * 16 + lr] = f2bf((acc[i][jj][r] + bv) * qs);
                }
        }
    } else {
        #pragma unroll
        for (int jj = 0; jj < 4; ++jj) {
            float bv = bias[n0 + jj * 16 + lr];
            #pragma unroll
            for (int i = 0; i < 4; ++i) {
                int s = s0 + i * 16 + quad * 4;
                s16x4 o;
                o.x = (short)f2bf(acc[i][jj][0] + bv);
                o.y = (short)f2bf(acc[i][jj][1] + bv);
                o.z = (short)f2bf(acc[i][jj][2] + bv);
                o.w = (short)f2bf(acc[i][jj][3] + bv);
                *(s16x4*)(VTo + ((size_t)(bb * NH + h) * HD + jj * 16 + lr) * S_ + s) = o;
            }
        }
    }
}

// ---------------- flash attention (causal, NO-max softmax, split-K 4 waves) ----------------
// Block = 4 waves, ALL on the same 32 q-rows; wave w handles K-tiles kt ≡ w (mod 4).
// Partials are additive (no-max softmax): 2-round LDS tree reduce, wave 0 stores.
// launch_bounds (256,3): 170 VGPR budget — (256,5) in R5 spilled 1 GB to scratch.
// V loads AFTER QK+mask: trims ~32 regs of peak pressure; latency hidden by exp/transpose.
__global__ __launch_bounds__(256, 3) void attn_kernel(
    const u16* __restrict__ Q, const u16* __restrict__ K,
    const u16* __restrict__ VT, u16* __restrict__ CTX)
{
    const int tid = threadIdx.x;
    const int wave = tid >> 6;
    const int lane = tid & 63;
    const int lr = lane & 15, quad = lane >> 4;
    const int xcd = blockIdx.x & 7;
    const int idx = blockIdx.x >> 3;            // 0..383
    const int bh  = xcd * 6 + (idx % 6);
    const int qw  = 63 - (idx / 6);             // longest q-chunks first
    const int q0  = qw * 32;
    const u16* Qb = Q  + (size_t)bh * S_ * HD;
    const u16* Kb = K  + (size_t)bh * S_ * HD;
    const u16* Vb = VT + (size_t)bh * HD * S_;

    // union: per-wave score transpose buf (4*16*68 floats) | reduction buf (2*64*44)
    __shared__ __align__(16) float smem[2 * 64 * 44];   // 5632 floats = 22528 B
    float* pbuf = smem + wave * (16 * 68);

    bf16x8 aq[2][2];
    #pragma unroll
    for (int mi = 0; mi < 2; ++mi)
        #pragma unroll
        for (int kk = 0; kk < 2; ++kk)
            aq[mi][kk] = *(const bf16x8*)(Qb + (size_t)(q0 + mi * 16 + lr) * HD + kk * 32 + quad * 8);

    f32x4 o[2][4] = {};
    f32x4 lacc[2] = {};
    bf16x8 ones;
    #pragma unroll
    for (int j = 0; j < 8; ++j) ones[j] = (short)0x3F80;   // bf16 1.0

    const int ktmax = (q0 + 31) >> 6;

    for (int kt = wave; kt <= ktmax; kt += 4) {
        const int k0 = kt << 6;

        bf16x8 bk[4][2];
        #pragma unroll
        for (int nt = 0; nt < 4; ++nt)
            #pragma unroll
            for (int kk = 0; kk < 2; ++kk)
                bk[nt][kk] = *(const bf16x8*)(Kb + (size_t)(k0 + nt * 16 + lr) * HD + kk * 32 + quad * 8);

        f32x4 sc[2][4];
        #pragma unroll
        for (int mi = 0; mi < 2; ++mi)
            #pragma unroll
            for (int nt = 0; nt < 4; ++nt) {
                f32x4 z = {0.f, 0.f, 0.f, 0.f};
                z = __builtin_amdgcn_mfma_f32_16x16x32_bf16(aq[mi][0], bk[nt][0], z, 0, 0, 0);
                z = __builtin_amdgcn_mfma_f32_16x16x32_bf16(aq[mi][1], bk[nt][1], z, 0, 0, 0);
                sc[mi][nt] = z;
            }

        if (kt == ktmax) {   // diagonal tile: causal mask (exp2(-inf) = 0)
            #pragma unroll
            for (int mi = 0; mi < 2; ++mi)
                #pragma unroll
                for (int nt = 0; nt < 4; ++nt)
                    #pragma unroll
                    for (int r = 0; r < 4; ++r) {
                        int row = q0 + mi * 16 + quad * 4 + r;
                        int col = k0 + nt * 16 + lr;
                        if (col > row) sc[mi][nt][r] = -INFINITY;
                    }
        }

        // V loads here: needed only at PV, ~300 cyc away behind exp/transpose work
        bf16x8 bv[4][2];
        #pragma unroll
        for (int nv = 0; nv < 4; ++nv)
            #pragma unroll
            for (int c = 0; c < 2; ++c)
                bv[nv][c] = *(const bf16x8*)(Vb + (size_t)(nv * 16 + lr) * S_ + k0 + c * 32 + quad * 8);

        // exp in C-layout; Q pre-scaled by scale*log2e
        #pragma unroll
        for (int mi = 0; mi < 2; ++mi)
            #pragma unroll
            for (int nt = 0; nt < 4; ++nt)
                #pragma unroll
                for (int r = 0; r < 4; ++r)
                    sc[mi][nt][r] = exp2f(sc[mi][nt][r]);

        // C-layout -> A-layout via per-wave LDS (wave-synchronous), mi sequential to halve LDS
        bf16x8 pa[2][2];
        #pragma unroll
        for (int mi = 0; mi < 2; ++mi) {
            #pragma unroll
            for (int r = 0; r < 4; ++r) {
                float* bp = &pbuf[(quad * 4 + r) * 68 + lr];
                bp[0]  = sc[mi][0][r];
                bp[16] = sc[mi][1][r];
                bp[32] = sc[mi][2][r];
                bp[48] = sc[mi][3][r];
            }
            #pragma unroll
            for (int c = 0; c < 2; ++c) {
                const float* rp = &pbuf[lr * 68 + c * 32 + quad * 8];
                union { unsigned u[4]; bf16x8 v; } P;
                #pragma unroll
                for (int p = 0; p < 4; ++p)
                    P.u[p] = pk2(rp[2 * p], rp[2 * p + 1]);
                pa[mi][c] = P.v;
            }
        }

        #pragma unroll
        for (int mi = 0; mi < 2; ++mi) {
            lacc[mi] = __builtin_amdgcn_mfma_f32_16x16x32_bf16(pa[mi][0], ones, lacc[mi], 0, 0, 0);
            lacc[mi] = __builtin_amdgcn_mfma_f32_16x16x32_bf16(pa[mi][1], ones, lacc[mi], 0, 0, 0);
            #pragma unroll
            for (int nv = 0; nv < 4; ++nv) {
                o[mi][nv] = __builtin_amdgcn_mfma_f32_16x16x32_bf16(pa[mi][0], bv[nv][0], o[mi][nv], 0, 0, 0);
                o[mi][nv] = __builtin_amdgcn_mfma_f32_16x16x32_bf16(pa[mi][1], bv[nv][1], o[mi][nv], 0, 0, 0);
            }
        }
    }

    // -------- cross-wave reduction (partials are additive) --------
    __syncthreads();
    float* red = smem;          // [2][64][44]
    if (wave >= 2) {
        float* rp = red + (wave - 2) * (64 * 44) + lane * 44;
        #pragma unroll
        for (int mi = 0; mi < 2; ++mi) {
            #pragma unroll
            for (int nv = 0; nv < 4; ++nv)
                *(f32x4*)(rp + (mi * 4 + nv) * 4) = o[mi][nv];
            *(f32x4*)(rp + 32 + mi * 4) = lacc[mi];
        }
    }
    __syncthreads();
    if (wave < 2) {
        const float* rp = red + wave * (64 * 44) + lane * 44;
        #pragma unroll
        for (int mi = 0; mi < 2; ++mi) {
            #pragma unroll
            for (int nv = 0; nv < 4; ++nv)
                o[mi][nv] += *(const f32x4*)(rp + (mi * 4 + nv) * 4);
            lacc[mi] += *(const f32x4*)(rp + 32 + mi * 4);
        }
    }
    __syncthreads();
    if (wave == 1) {
        float* rp = red + lane * 44;
        #pragma unroll
        for (int mi = 0; mi < 2; ++mi) {
            #pragma unroll
            for (int nv = 0; nv < 4; ++nv)
                *(f32x4*)(rp + (mi * 4 + nv) * 4) = o[mi][nv];
            *(f32x4*)(rp + 32 + mi * 4) = lacc[mi];
        }
    }
    __syncthreads();
    if (wave == 0) {
        const float* rp = red + lane * 44;
        #pragma unroll
        for (int mi = 0; mi < 2; ++mi) {
            #pragma unroll
            for (int nv = 0; nv < 4; ++nv)
                o[mi][nv] += *(const f32x4*)(rp + (mi * 4 + nv) * 4);
            lacc[mi] += *(const f32x4*)(rp + 32 + mi * 4);
        }
        const int bb = bh / NH, h = bh % NH;
        #pragma unroll
        for (int mi = 0; mi < 2; ++mi) {
            f32x4 inv;
            #pragma unroll
            for (int r = 0; r < 4; ++r) inv[r] = 1.0f / lacc[mi][r];
            #pragma unroll
            for (int nv = 0; nv < 4; ++nv)
                #pragma unroll
                for (int r = 0; r < 4; ++r)
                    CTX[(size_t)(bb * S_ + q0 + mi * 16 + quad * 4 + r) * DM + h * HD + nv * 16 + lr]
                        = f2bf(o[mi][nv][r] * inv[r]);
        }
    }
}

// ---------------- output projection GEMM (LDS-staged, fp32 out) ----------------
__global__ __launch_bounds__(256) void o_gemm(
    const u16* __restrict__ X, const u16* __restrict__ W,
    const float* __restrict__ bias, float* __restrict__ Out)
{
    __shared__ __align__(16) u16 As[128 * 32];
    __shared__ __align__(16) u16 Bs[128 * 32];

    const int mt = blockIdx.x / 6, nt = blockIdx.x % 6;
    const int lane = threadIdx.x & 63;
    const int lr = lane & 15, quad = lane >> 4;
    const int wave = threadIdx.x >> 6;
    const int m0 = mt * 128 + (wave & 1) * 64;
    const int n0 = nt * 128 + (wave >> 1) * 64;

    f32x4 acc[4][4] = {};
    gemm_core_128(X, W, mt * 128, nt * 128, As, Bs, acc);

    #pragma unroll
    for (int jj = 0; jj < 4; ++jj) {
        float bv = bias[n0 + jj * 16 + lr];
        #pragma unroll
        for (int i = 0; i < 4; ++i)
            #pragma unroll
            for (int r = 0; r < 4; ++r)
                Out[(size_t)(m0 + i * 16 + quad * 4 + r) * DM + n0 + jj * 16 + lr] = acc[i][jj][r] + bv;
    }
}

extern "C" void kernel_launch(void* const* d_in, const int* in_sizes, int n_in,
                              void* d_out, int out_size, void* d_ws, size_t ws_size,
                              hipStream_t stream) {
    const float* q  = (const float*)d_in[0];
    const float* k  = (const float*)d_in[1];
    const float* v  = (const float*)d_in[2];
    const float* WQ = (const float*)d_in[3];
    const float* bQ = (const float*)d_in[4];
    const float* WK = (const float*)d_in[5];
    const float* bK = (const float*)d_in[6];
    const float* WV = (const float*)d_in[7];
    const float* bV = (const float*)d_in[8];
    const float* WO = (const float*)d_in[9];
    const float* bO = (const float*)d_in[10];

    char* ws = (char*)d_ws;
    const size_t SZ_X = (size_t)MT * DM * 2;   // 12,582,912 B
    const size_t SZ_W = (size_t)DM * DM * 2;   //  1,179,648 B
    u16* Xq = (u16*)(ws);
    u16* Xk = (u16*)(ws + SZ_X);
    u16* Xv = (u16*)(ws + 2 * SZ_X);
    u16* Wq = (u16*)(ws + 3 * SZ_X);
    u16* Wk = (u16*)(ws + 3 * SZ_X + SZ_W);
    u16* Wv = (u16*)(ws + 3 * SZ_X + 2 * SZ_W);
    u16* Wo = (u16*)(ws + 3 * SZ_X + 3 * SZ_W);
    u16* Qh  = (u16*)(ws + 3 * SZ_X + 4 * SZ_W);
    u16* Kh  = (u16*)(ws + 4 * SZ_X + 4 * SZ_W);
    u16* VTh = (u16*)(ws + 5 * SZ_X + 4 * SZ_W);
    u16* CTX = Xq;   // Xq dead after qkv_gemm; reuse

    const int nX = MT * DM;    // 6,291,456
    const int nW = DM * DM;    //   589,824
    cvt3_kernel<<<3 * (nX / 1024), 256, 0, stream>>>(q, k, v, Xq, Xk, Xv, nX / 1024);
    cvt4_kernel<<<4 * (nW / 1024), 256, 0, stream>>>(WQ, WK, WV, WO, Wq, Wk, Wv, Wo, nW / 1024);

    qkv_gemm<<<1152, 256, 0, stream>>>(Xq, Xk, Xv, Wq, Wk, Wv, bQ, bK, bV, Qh, Kh, VTh);
    attn_kernel<<<3072, 256, 0, stream>>>(Qh, Kh, VTh, CTX);
    o_gemm<<<384, 256, 0, stream>>>(CTX, Wo, bO, (float*)d_out);
}